// Round 2
// baseline (685.121 us; speedup 1.0000x reference)
//
#include <hip/hip_runtime.h>
#include <math.h>

#define Bc 16
#define Cc 96
#define Hh 128
#define Ww 128
#define NPIX 16384
#define Mm 12
#define CR 6
#define PAD 3

// -------------------- K1: depthwise 7x7 conv + bias, per-block pool partials
__global__ __launch_bounds__(256) void k_conv(const float* __restrict__ x,
        const float* __restrict__ dw_w, const float* __restrict__ dw_b,
        float* __restrict__ f, float* __restrict__ partial) {
    const int bc = blockIdx.z;             // b*Cc + c
    const int c = bc % Cc;
    __shared__ float tile[22][24];
    __shared__ float wts[49];
    __shared__ float red[256];
    const int tx = threadIdx.x, ty = threadIdx.y;
    const int tid = ty * 16 + tx;
    if (tid < 49) wts[tid] = dw_w[c * 49 + tid];
    const int ox0 = blockIdx.x * 16, oy0 = blockIdx.y * 16;
    const float* xp = x + (size_t)bc * NPIX;
    for (int i = tid; i < 22 * 22; i += 256) {
        int ly = i / 22, lx = i % 22;
        int gy = oy0 + ly - PAD, gx = ox0 + lx - PAD;
        float v = 0.f;
        if (gy >= 0 && gy < Hh && gx >= 0 && gx < Ww) v = xp[gy * Ww + gx];
        tile[ly][lx] = v;
    }
    __syncthreads();
    float acc = dw_b[c];
    #pragma unroll
    for (int ky = 0; ky < 7; ++ky)
        #pragma unroll
        for (int kx = 0; kx < 7; ++kx)
            acc = fmaf(tile[ty + ky][tx + kx], wts[ky * 7 + kx], acc);
    f[(size_t)bc * NPIX + (oy0 + ty) * Ww + (ox0 + tx)] = acc;
    red[tid] = acc;
    __syncthreads();
    for (int s = 128; s > 0; s >>= 1) {
        if (tid < s) red[tid] += red[tid + s];
        __syncthreads();
    }
    if (tid == 0) partial[bc * 64 + blockIdx.y * 8 + blockIdx.x] = red[0];
}

// -------------------- K2: pooled mean -> SE attention
__global__ void k_attn(const float* __restrict__ partial,
        const float* __restrict__ ca_w1, const float* __restrict__ ca_w2,
        float* __restrict__ attn) {
    __shared__ float pm[Cc];
    __shared__ float hh[CR];
    const int tid = threadIdx.x;
    const int b = blockIdx.x;
    if (tid < Cc) {
        float s = 0.f;
        const float* p = partial + (b * Cc + tid) * 64;
        #pragma unroll
        for (int i = 0; i < 64; ++i) s += p[i];
        pm[tid] = s * (1.0f / (float)NPIX);
    }
    __syncthreads();
    if (tid < CR) {
        float s = 0.f;
        for (int c0 = 0; c0 < Cc; ++c0) s = fmaf(ca_w1[tid * Cc + c0], pm[c0], s);
        hh[tid] = fmaxf(s, 0.f);
    }
    __syncthreads();
    if (tid < Cc) {
        float s = 0.f;
        #pragma unroll
        for (int r = 0; r < CR; ++r) s = fmaf(ca_w2[tid * CR + r], hh[r], s);
        attn[b * Cc + tid] = 1.0f / (1.0f + expf(-s));
    }
}

// -------------------- K3: attn-scale + exact GELU + channel-LN + offset proj
__global__ __launch_bounds__(256) void k_ln_off(const float* __restrict__ f,
        const float* __restrict__ attn, const float* __restrict__ ln_g,
        const float* __restrict__ ln_b, const float* __restrict__ off_w,
        float* __restrict__ offs) {
    __shared__ float sa[Cc], sg[Cc], sb[Cc], sw0[Cc], sw1[Cc];
    const int tid = threadIdx.x;
    const int b = blockIdx.x >> 6;
    const int pix = ((blockIdx.x & 63) << 8) + tid;
    if (tid < Cc) {
        sa[tid] = attn[b * Cc + tid];
        sg[tid] = ln_g[tid];
        sb[tid] = ln_b[tid];
        sw0[tid] = off_w[tid];
        sw1[tid] = off_w[Cc + tid];
    }
    __syncthreads();
    const float* fp = f + (size_t)b * Cc * NPIX + pix;
    float u[Cc];
    float s1 = 0.f;
    #pragma unroll
    for (int c = 0; c < Cc; ++c) {
        float v = fp[(size_t)c * NPIX] * sa[c];
        float g = 0.5f * v * (1.0f + erff(v * 0.70710678118654752440f));
        u[c] = g;
        s1 += g;
    }
    float mu = s1 * (1.0f / (float)Cc);
    float s2 = 0.f;
    #pragma unroll
    for (int c = 0; c < Cc; ++c) { float d = u[c] - mu; s2 = fmaf(d, d, s2); }
    float rs = rsqrtf(s2 * (1.0f / (float)Cc) + 1e-5f);
    float o0 = 0.f, o1 = 0.f;
    #pragma unroll
    for (int c = 0; c < Cc; ++c) {
        float v = (u[c] - mu) * rs * sg[c] + sb[c];
        o0 = fmaf(sw0[c], v, o0);
        o1 = fmaf(sw1[c], v, o1);
    }
    offs[(size_t)b * 2 * NPIX + pix] = o0;
    offs[(size_t)b * 2 * NPIX + NPIX + pix] = o1;
}

// -------------------- K4: cosine-sim cluster assignment in FP64
// argmax_m (x/||x||)·(c_m/||c_m||): the per-pixel 1/||x|| factor is a
// positive scalar -> cannot change the argmax -> skip it entirely.
// f64 dot noise (~1e-15) << f32-scale top-2 gaps, so the argmax matches
// the harness's f64 numpy reference deterministically.
__global__ __launch_bounds__(256) void k_group(const float* __restrict__ x,
        const float* __restrict__ centers, int* __restrict__ gid) {
    __shared__ double scn[Mm * Cc];
    const int tid = threadIdx.x;
    for (int i = tid; i < Mm * Cc; i += 256) scn[i] = (double)centers[i];
    __syncthreads();
    if (tid < Mm) {
        double ss = 0.0;
        #pragma unroll
        for (int c = 0; c < Cc; ++c) { double v = scn[tid * Cc + c]; ss += v * v; }
        double inv = 1.0 / fmax(sqrt(ss), 1e-12);
        #pragma unroll
        for (int c = 0; c < Cc; ++c) scn[tid * Cc + c] *= inv;
    }
    __syncthreads();
    const int b = blockIdx.x >> 6;
    const int n = ((blockIdx.x & 63) << 8) + tid;
    const float* xp = x + (size_t)b * Cc * NPIX + n;
    double acc[Mm];
    #pragma unroll
    for (int m = 0; m < Mm; ++m) acc[m] = 0.0;
    for (int c = 0; c < Cc; ++c) {
        double xv = (double)xp[(size_t)c * NPIX];
        #pragma unroll
        for (int m = 0; m < Mm; ++m) acc[m] = fma(xv, scn[m * Cc + c], acc[m]);
    }
    int bi = 0;
    double bv = acc[0];
    #pragma unroll
    for (int m = 1; m < Mm; ++m) {
        if (acc[m] > bv) { bv = acc[m]; bi = m; }
    }
    gid[(size_t)b * NPIX + n] = bi;
}

// -------------------- K5: stable counting sort by group id (per batch)
__global__ __launch_bounds__(256) void k_sort(const int* __restrict__ gid,
                                              int* __restrict__ perm) {
    __shared__ int hist[256 * Mm];
    __shared__ int tot[Mm];
    const int t = threadIdx.x;
    const int b = blockIdx.x;
    for (int i = t; i < 256 * Mm; i += 256) hist[i] = 0;
    __syncthreads();
    const int* gp = gid + (size_t)b * NPIX;
    const int base = t * 64;
    for (int i = 0; i < 64; ++i) hist[t * Mm + gp[base + i]] += 1;
    __syncthreads();
    if (t < Mm) {
        int run = 0;
        for (int r = 0; r < 256; ++r) {
            int v = hist[r * Mm + t];
            hist[r * Mm + t] = run;
            run += v;
        }
        tot[t] = run;
    }
    __syncthreads();
    if (t == 0) {
        int run = 0;
        for (int m = 0; m < Mm; ++m) { int v = tot[m]; tot[m] = run; run += v; }
    }
    __syncthreads();
    int* pp = perm + (size_t)b * NPIX;
    for (int i = 0; i < 64; ++i) {
        int g = gp[base + i];
        int pos = tot[g] + hist[t * Mm + g];
        hist[t * Mm + g] += 1;
        pp[pos] = base + i;
    }
}

// -------------------- K6: bilinear grid sample of x (+ R bias), writes x_bar
__global__ __launch_bounds__(256) void k_sample(const float* __restrict__ x,
        const float* __restrict__ R, const float* __restrict__ offs,
        float* __restrict__ xbar) {
    const int tid = threadIdx.x;
    const int b = blockIdx.x >> 6;
    const int pix = ((blockIdx.x & 63) << 8) + tid;
    const int hh = pix >> 7, wwp = pix & 127;
    float o0 = offs[(size_t)b * 2 * NPIX + pix];
    float o1 = offs[(size_t)b * 2 * NPIX + NPIX + pix];
    float gx = -1.0f + (float)wwp * (2.0f / 127.0f) + o0;
    float gy = -1.0f + (float)hh * (2.0f / 127.0f) + o1;
    float px = fminf(fmaxf((gx + 1.0f) * ((float)Ww * 0.5f) - 0.5f, 0.0f), (float)(Ww - 1));
    float py = fminf(fmaxf((gy + 1.0f) * ((float)Hh * 0.5f) - 0.5f, 0.0f), (float)(Hh - 1));
    float x0f = floorf(px), y0f = floorf(py);
    float wx = px - x0f, wy = py - y0f;
    int x0 = (int)x0f, y0 = (int)y0f;
    int x1 = min(x0 + 1, Ww - 1), y1 = min(y0 + 1, Hh - 1);
    int i00 = y0 * Ww + x0, i01 = y0 * Ww + x1;
    int i10 = y1 * Ww + x0, i11 = y1 * Ww + x1;
    float rb;
    {
        float v00 = R[i00], v01 = R[i01], v10 = R[i10], v11 = R[i11];
        float top = v00 * (1.0f - wx) + v01 * wx;
        float bot = v10 * (1.0f - wx) + v11 * wx;
        rb = top * (1.0f - wy) + bot * wy;
    }
    const float* xp = x + (size_t)b * Cc * NPIX;
    float* op = xbar + (size_t)b * Cc * NPIX + pix;
    for (int c = 0; c < Cc; ++c) {
        const float* xc = xp + (size_t)c * NPIX;
        float v00 = xc[i00], v01 = xc[i01], v10 = xc[i10], v11 = xc[i11];
        float top = v00 * (1.0f - wx) + v01 * wx;
        float bot = v10 * (1.0f - wx) + v11 * wx;
        op[(size_t)c * NPIX] = top * (1.0f - wy) + bot * wy + rb;
    }
}

// -------------------- K7: apply permutation per (b,c) plane, in place via LDS
__global__ __launch_bounds__(256) void k_gather(const float* __restrict__ xbar,
        const int* __restrict__ perm, float* __restrict__ out) {
    __shared__ float plane[NPIX];
    const int c = blockIdx.x, b = blockIdx.y;
    const float* sp = xbar + ((size_t)b * Cc + c) * NPIX;
    for (int i = threadIdx.x; i < NPIX; i += 256) plane[i] = sp[i];
    __syncthreads();
    const int* pp = perm + (size_t)b * NPIX;
    float* op = out + ((size_t)b * Cc + c) * NPIX;
    for (int j = threadIdx.x; j < NPIX; j += 256) op[j] = plane[pp[j]];
}

// -------------------- K8: tail outputs (perm as float, centers copy)
__global__ void k_tail(const int* __restrict__ perm,
        const float* __restrict__ centers, float* __restrict__ out) {
    const int i = blockIdx.x * 256 + threadIdx.x;
    const size_t mapN = (size_t)Bc * Cc * NPIX;
    if (i < Bc * NPIX) out[mapN + i] = (float)perm[i];
    const int j = i - Bc * NPIX;
    if (j >= 0 && j < Mm * Cc) out[mapN + Bc * NPIX + j] = centers[j];
}

extern "C" void kernel_launch(void* const* d_in, const int* in_sizes, int n_in,
                              void* d_out, int out_size, void* d_ws, size_t ws_size,
                              hipStream_t stream) {
    const float* x       = (const float*)d_in[0];
    const float* dw_w    = (const float*)d_in[1];
    const float* dw_b    = (const float*)d_in[2];
    const float* ca_w1   = (const float*)d_in[3];
    const float* ca_w2   = (const float*)d_in[4];
    const float* ln_g    = (const float*)d_in[5];
    const float* ln_b    = (const float*)d_in[6];
    const float* off_w   = (const float*)d_in[7];
    const float* R       = (const float*)d_in[8];
    const float* centers = (const float*)d_in[9];
    float* out = (float*)d_out;

    // workspace layout (all fp32 / int32), ~4.6 MB total
    float* partial = (float*)d_ws;              // Bc*Cc*64
    float* attn    = partial + Bc * Cc * 64;    // Bc*Cc
    float* offs    = attn + Bc * Cc;            // Bc*2*NPIX
    int*   gid     = (int*)(offs + Bc * 2 * NPIX); // Bc*NPIX
    int*   perm    = gid + Bc * NPIX;              // Bc*NPIX

    // conv output f lives in d_out's map region; later overwritten by x_bar,
    // then permuted in place (per-plane LDS staging makes in-place safe).
    float* f = out;

    hipLaunchKernelGGL(k_conv, dim3(8, 8, Bc * Cc), dim3(16, 16), 0, stream,
                       x, dw_w, dw_b, f, partial);
    hipLaunchKernelGGL(k_attn, dim3(Bc), dim3(128), 0, stream,
                       partial, ca_w1, ca_w2, attn);
    hipLaunchKernelGGL(k_ln_off, dim3(1024), dim3(256), 0, stream,
                       f, attn, ln_g, ln_b, off_w, offs);
    hipLaunchKernelGGL(k_group, dim3(1024), dim3(256), 0, stream, x, centers, gid);
    hipLaunchKernelGGL(k_sort, dim3(Bc), dim3(256), 0, stream, gid, perm);
    hipLaunchKernelGGL(k_sample, dim3(1024), dim3(256), 0, stream, x, R, offs, f);
    hipLaunchKernelGGL(k_gather, dim3(Cc, Bc), dim3(256), 0, stream, f, perm, out);
    hipLaunchKernelGGL(k_tail, dim3((Bc * NPIX + Mm * Cc + 255) / 256), dim3(256),
                       0, stream, perm, centers, out);
}

// Round 3
// 482.217 us; speedup vs baseline: 1.4208x; 1.4208x over previous
//
#include <hip/hip_runtime.h>
#include <math.h>

#define Bc 16
#define Cc 96
#define Hh 128
#define Ww 128
#define NPIX 16384
#define Mm 12
#define CR 6
#define PAD 3

// -------------------- K1: depthwise 7x7 conv + bias, per-block pool partials
__global__ __launch_bounds__(256) void k_conv(const float* __restrict__ x,
        const float* __restrict__ dw_w, const float* __restrict__ dw_b,
        float* __restrict__ f, float* __restrict__ partial) {
    const int bc = blockIdx.z;             // b*Cc + c
    const int c = bc % Cc;
    __shared__ float tile[22][24];
    __shared__ float wts[49];
    __shared__ float red[256];
    const int tx = threadIdx.x, ty = threadIdx.y;
    const int tid = ty * 16 + tx;
    if (tid < 49) wts[tid] = dw_w[c * 49 + tid];
    const int ox0 = blockIdx.x * 16, oy0 = blockIdx.y * 16;
    const float* xp = x + (size_t)bc * NPIX;
    for (int i = tid; i < 22 * 22; i += 256) {
        int ly = i / 22, lx = i % 22;
        int gy = oy0 + ly - PAD, gx = ox0 + lx - PAD;
        float v = 0.f;
        if (gy >= 0 && gy < Hh && gx >= 0 && gx < Ww) v = xp[gy * Ww + gx];
        tile[ly][lx] = v;
    }
    __syncthreads();
    float acc = dw_b[c];
    #pragma unroll
    for (int ky = 0; ky < 7; ++ky)
        #pragma unroll
        for (int kx = 0; kx < 7; ++kx)
            acc = fmaf(tile[ty + ky][tx + kx], wts[ky * 7 + kx], acc);
    f[(size_t)bc * NPIX + (oy0 + ty) * Ww + (ox0 + tx)] = acc;
    red[tid] = acc;
    __syncthreads();
    for (int s = 128; s > 0; s >>= 1) {
        if (tid < s) red[tid] += red[tid + s];
        __syncthreads();
    }
    if (tid == 0) partial[bc * 64 + blockIdx.y * 8 + blockIdx.x] = red[0];
}

// -------------------- K2: pooled mean -> SE attention; + centers copy to out
__global__ void k_attn(const float* __restrict__ partial,
        const float* __restrict__ ca_w1, const float* __restrict__ ca_w2,
        const float* __restrict__ centers,
        float* __restrict__ attn, float* __restrict__ out) {
    __shared__ float pm[Cc];
    __shared__ float hh[CR];
    const int tid = threadIdx.x;
    const int b = blockIdx.x;
    if (b == 0) {  // centers copy (output 2)
        const size_t base = (size_t)Bc * Cc * NPIX + (size_t)Bc * NPIX;
        for (int i = tid; i < Mm * Cc; i += 128) out[base + i] = centers[i];
    }
    if (tid < Cc) {
        float s = 0.f;
        const float* p = partial + (b * Cc + tid) * 64;
        #pragma unroll
        for (int i = 0; i < 64; ++i) s += p[i];
        pm[tid] = s * (1.0f / (float)NPIX);
    }
    __syncthreads();
    if (tid < CR) {
        float s = 0.f;
        for (int c0 = 0; c0 < Cc; ++c0) s = fmaf(ca_w1[tid * Cc + c0], pm[c0], s);
        hh[tid] = fmaxf(s, 0.f);
    }
    __syncthreads();
    if (tid < Cc) {
        float s = 0.f;
        #pragma unroll
        for (int r = 0; r < CR; ++r) s = fmaf(ca_w2[tid * CR + r], hh[r], s);
        attn[b * Cc + tid] = 1.0f / (1.0f + expf(-s));
    }
}

// fast exact-enough erf (Abramowitz-Stegun 7.1.26, |err|<=1.5e-7)
__device__ __forceinline__ float fast_gelu(float v) {
    float z = fabsf(v) * 0.70710678118654752440f;
    float t = 1.0f / fmaf(0.3275911f, z, 1.0f);
    float poly = t * fmaf(t, fmaf(t, fmaf(t, fmaf(t, 1.061405429f, -1.453152027f),
                          1.421413741f), -0.284496736f), 0.254829592f);
    float e = exp2f(-1.44269504088896340736f * z * z);
    float erfz = 1.0f - poly * e;
    erfz = (v < 0.0f) ? -erfz : erfz;
    return 0.5f * v * (1.0f + erfz);
}

// -------------------- K3: attn-scale + GELU + channel-LN + offset proj
__global__ __launch_bounds__(256) void k_ln_off(const float* __restrict__ f,
        const float* __restrict__ attn, const float* __restrict__ ln_g,
        const float* __restrict__ ln_b, const float* __restrict__ off_w,
        float* __restrict__ offs) {
    __shared__ float sa[Cc], sg[Cc], sb[Cc], sw0[Cc], sw1[Cc];
    const int tid = threadIdx.x;
    const int b = blockIdx.x >> 6;
    const int pix = ((blockIdx.x & 63) << 8) + tid;
    if (tid < Cc) {
        sa[tid] = attn[b * Cc + tid];
        sg[tid] = ln_g[tid];
        sb[tid] = ln_b[tid];
        sw0[tid] = off_w[tid];
        sw1[tid] = off_w[Cc + tid];
    }
    __syncthreads();
    const float* fp = f + (size_t)b * Cc * NPIX + pix;
    float u[Cc];
    float s1 = 0.f;
    #pragma unroll
    for (int c = 0; c < Cc; ++c) {
        float g = fast_gelu(fp[(size_t)c * NPIX] * sa[c]);
        u[c] = g;
        s1 += g;
    }
    float mu = s1 * (1.0f / (float)Cc);
    float s2 = 0.f;
    #pragma unroll
    for (int c = 0; c < Cc; ++c) { float d = u[c] - mu; s2 = fmaf(d, d, s2); }
    float rs = rsqrtf(s2 * (1.0f / (float)Cc) + 1e-5f);
    float o0 = 0.f, o1 = 0.f;
    #pragma unroll
    for (int c = 0; c < Cc; ++c) {
        float v = (u[c] - mu) * rs * sg[c] + sb[c];
        o0 = fmaf(sw0[c], v, o0);
        o1 = fmaf(sw1[c], v, o1);
    }
    offs[(size_t)b * 2 * NPIX + pix] = o0;
    offs[(size_t)b * 2 * NPIX + NPIX + pix] = o1;
}

// -------------------- K4: cosine-sim cluster assignment in FP64
// per-pixel 1/||x|| is a positive scalar -> cannot change argmax -> skipped.
__global__ __launch_bounds__(256) void k_group(const float* __restrict__ x,
        const float* __restrict__ centers, int* __restrict__ gid) {
    __shared__ double scn[Mm * Cc];
    const int tid = threadIdx.x;
    for (int i = tid; i < Mm * Cc; i += 256) scn[i] = (double)centers[i];
    __syncthreads();
    if (tid < Mm) {
        double ss = 0.0;
        #pragma unroll
        for (int c = 0; c < Cc; ++c) { double v = scn[tid * Cc + c]; ss += v * v; }
        double inv = 1.0 / fmax(sqrt(ss), 1e-12);
        #pragma unroll
        for (int c = 0; c < Cc; ++c) scn[tid * Cc + c] *= inv;
    }
    __syncthreads();
    const int b = blockIdx.x >> 6;
    const int n = ((blockIdx.x & 63) << 8) + tid;
    const float* xp = x + (size_t)b * Cc * NPIX + n;
    double acc[Mm];
    #pragma unroll
    for (int m = 0; m < Mm; ++m) acc[m] = 0.0;
    for (int c = 0; c < Cc; ++c) {
        double xv = (double)xp[(size_t)c * NPIX];
        #pragma unroll
        for (int m = 0; m < Mm; ++m) acc[m] = fma(xv, scn[m * Cc + c], acc[m]);
    }
    int bi = 0;
    double bv = acc[0];
    #pragma unroll
    for (int m = 1; m < Mm; ++m) {
        if (acc[m] > bv) { bv = acc[m]; bi = m; }
    }
    gid[(size_t)b * NPIX + n] = bi;
}

// -------------------- K5: stable counting sort -> inverse perm + float perm out
__global__ __launch_bounds__(256) void k_sort(const int* __restrict__ gid,
        int* __restrict__ iperm, float* __restrict__ out) {
    __shared__ int hist[256 * Mm];
    __shared__ int tot[Mm];
    const int t = threadIdx.x;
    const int b = blockIdx.x;
    for (int i = t; i < 256 * Mm; i += 256) hist[i] = 0;
    __syncthreads();
    const int* gp = gid + (size_t)b * NPIX;
    const int base = t * 64;
    for (int i = 0; i < 64; ++i) hist[t * Mm + gp[base + i]] += 1;
    __syncthreads();
    if (t < Mm) {
        int run = 0;
        for (int r = 0; r < 256; ++r) {
            int v = hist[r * Mm + t];
            hist[r * Mm + t] = run;
            run += v;
        }
        tot[t] = run;
    }
    __syncthreads();
    if (t == 0) {
        int run = 0;
        for (int m = 0; m < Mm; ++m) { int v = tot[m]; tot[m] = run; run += v; }
    }
    __syncthreads();
    int* ip = iperm + (size_t)b * NPIX;
    float* fperm = out + (size_t)Bc * Cc * NPIX + (size_t)b * NPIX;
    for (int i = 0; i < 64; ++i) {
        int src = base + i;
        int g = gp[src];
        int pos = tot[g] + hist[t * Mm + g];
        hist[t * Mm + g] += 1;
        ip[src] = pos;            // inverse permutation (scatter destination)
        fperm[pos] = (float)src;  // output 1: perm_indices as float
    }
}

// -------------------- K6: bilinear sample of x (+R bias), scatter via iperm
// XCD-chunked swizzle: each XCD gets 128 consecutive pixel-bands (2 batches)
// so the jittered sampling windows of adjacent bands share that XCD's L2.
__global__ __launch_bounds__(256) void k_sample(const float* __restrict__ x,
        const float* __restrict__ R, const float* __restrict__ offs,
        const int* __restrict__ iperm, float* __restrict__ out) {
    const int lin = blockIdx.x;                    // 0..1023
    const int swz = (lin & 7) * 128 + (lin >> 3);  // bijective (1024 = 8*128)
    const int tid = threadIdx.x;
    const int b = swz >> 6;
    const int pix = ((swz & 63) << 8) + tid;
    const int hh = pix >> 7, wwp = pix & 127;
    float o0 = offs[(size_t)b * 2 * NPIX + pix];
    float o1 = offs[(size_t)b * 2 * NPIX + NPIX + pix];
    float gx = -1.0f + (float)wwp * (2.0f / 127.0f) + o0;
    float gy = -1.0f + (float)hh * (2.0f / 127.0f) + o1;
    float px = fminf(fmaxf((gx + 1.0f) * ((float)Ww * 0.5f) - 0.5f, 0.0f), (float)(Ww - 1));
    float py = fminf(fmaxf((gy + 1.0f) * ((float)Hh * 0.5f) - 0.5f, 0.0f), (float)(Hh - 1));
    float x0f = floorf(px), y0f = floorf(py);
    float wx = px - x0f, wy = py - y0f;
    int x0 = (int)x0f, y0 = (int)y0f;
    int x1 = min(x0 + 1, Ww - 1), y1 = min(y0 + 1, Hh - 1);
    int i00 = y0 * Ww + x0, i01 = y0 * Ww + x1;
    int i10 = y1 * Ww + x0, i11 = y1 * Ww + x1;
    float rb;
    {
        float v00 = R[i00], v01 = R[i01], v10 = R[i10], v11 = R[i11];
        float top = v00 * (1.0f - wx) + v01 * wx;
        float bot = v10 * (1.0f - wx) + v11 * wx;
        rb = top * (1.0f - wy) + bot * wy;
    }
    const int j = iperm[(size_t)b * NPIX + pix];
    const float* xp = x + (size_t)b * Cc * NPIX;
    float* op = out + (size_t)b * Cc * NPIX + j;
    for (int c = 0; c < Cc; ++c) {
        const float* xc = xp + (size_t)c * NPIX;
        float v00 = xc[i00], v01 = xc[i01], v10 = xc[i10], v11 = xc[i11];
        float top = v00 * (1.0f - wx) + v01 * wx;
        float bot = v10 * (1.0f - wx) + v11 * wx;
        op[(size_t)c * NPIX] = top * (1.0f - wy) + bot * wy + rb;
    }
}

extern "C" void kernel_launch(void* const* d_in, const int* in_sizes, int n_in,
                              void* d_out, int out_size, void* d_ws, size_t ws_size,
                              hipStream_t stream) {
    const float* x       = (const float*)d_in[0];
    const float* dw_w    = (const float*)d_in[1];
    const float* dw_b    = (const float*)d_in[2];
    const float* ca_w1   = (const float*)d_in[3];
    const float* ca_w2   = (const float*)d_in[4];
    const float* ln_g    = (const float*)d_in[5];
    const float* ln_b    = (const float*)d_in[6];
    const float* off_w   = (const float*)d_in[7];
    const float* R       = (const float*)d_in[8];
    const float* centers = (const float*)d_in[9];
    float* out = (float*)d_out;

    // workspace layout (~4.6 MB)
    float* partial = (float*)d_ws;                 // Bc*Cc*64
    float* attn    = partial + Bc * Cc * 64;       // Bc*Cc
    float* offs    = attn + Bc * Cc;               // Bc*2*NPIX
    int*   gid     = (int*)(offs + Bc * 2 * NPIX); // Bc*NPIX
    int*   iperm   = gid + Bc * NPIX;              // Bc*NPIX

    // conv output f lives in d_out's map region; dead after k_ln_off, then
    // safely overwritten by k_sample's permuted scatter writes.
    float* f = out;

    hipLaunchKernelGGL(k_conv, dim3(8, 8, Bc * Cc), dim3(16, 16), 0, stream,
                       x, dw_w, dw_b, f, partial);
    hipLaunchKernelGGL(k_attn, dim3(Bc), dim3(128), 0, stream,
                       partial, ca_w1, ca_w2, centers, attn, out);
    hipLaunchKernelGGL(k_ln_off, dim3(1024), dim3(256), 0, stream,
                       f, attn, ln_g, ln_b, off_w, offs);
    hipLaunchKernelGGL(k_group, dim3(1024), dim3(256), 0, stream, x, centers, gid);
    hipLaunchKernelGGL(k_sort, dim3(Bc), dim3(256), 0, stream, gid, iperm, out);
    hipLaunchKernelGGL(k_sample, dim3(1024), dim3(256), 0, stream,
                       x, R, offs, iperm, out);
}

// Round 4
// 374.964 us; speedup vs baseline: 1.8272x; 1.2860x over previous
//
#include <hip/hip_runtime.h>
#include <math.h>

#define Bc 16
#define Cc 96
#define Hh 128
#define Ww 128
#define NPIX 16384
#define Mm 12
#define CR 6
#define PAD 3

// conv tile geometry: 32 rows x 64 cols of output per 256-thread block,
// each thread produces 8 horizontal outputs via in-register sliding window.
#define CTH 32
#define CTW 64
#define TROWS 38          // CTH + 6
#define TCOLS 70          // CTW + 6
#define TSTRIDE 76        // padded: bank-group (3*ty+2*tx)%8 uniform -> conflict-free

// -------------------- K1: depthwise 7x7 conv + bias, per-block pool partials
__global__ __launch_bounds__(256) void k_conv(const float* __restrict__ x,
        const float* __restrict__ dw_w, const float* __restrict__ dw_b,
        float* __restrict__ f, float* __restrict__ partial) {
    const int bc = blockIdx.z;             // b*Cc + c
    const int c = bc % Cc;
    __shared__ float tile[TROWS * TSTRIDE];
    __shared__ float wts[49];
    __shared__ float red[256];
    const int tid = threadIdx.x;
    if (tid < 49) wts[tid] = dw_w[c * 49 + tid];
    const int ox0 = blockIdx.x * CTW, oy0 = blockIdx.y * CTH;
    const float* xp = x + (size_t)bc * NPIX;
    for (int i = tid; i < TROWS * TCOLS; i += 256) {
        int r = i / TCOLS, cc2 = i % TCOLS;
        int gy = oy0 + r - PAD, gx = ox0 + cc2 - PAD;
        float v = 0.f;
        if (gy >= 0 && gy < Hh && gx >= 0 && gx < Ww) v = xp[gy * Ww + gx];
        tile[r * TSTRIDE + cc2] = v;
    }
    __syncthreads();
    const int tx = tid & 7;    // col-group: outputs ox0 + tx*8 + 0..7
    const int ty = tid >> 3;   // output row 0..31
    const float bias = dw_b[c];
    float acc[8];
    #pragma unroll
    for (int j = 0; j < 8; ++j) acc[j] = bias;
    #pragma unroll
    for (int ky = 0; ky < 7; ++ky) {
        const float* rowp = &tile[(ty + ky) * TSTRIDE + tx * 8];
        float4 a = *(const float4*)(rowp);
        float4 b4 = *(const float4*)(rowp + 4);
        float4 c4 = *(const float4*)(rowp + 8);
        float4 d4 = *(const float4*)(rowp + 12);
        float win[16] = {a.x, a.y, a.z, a.w, b4.x, b4.y, b4.z, b4.w,
                         c4.x, c4.y, c4.z, c4.w, d4.x, d4.y, d4.z, d4.w};
        #pragma unroll
        for (int kx = 0; kx < 7; ++kx) {
            float w = wts[ky * 7 + kx];
            #pragma unroll
            for (int j = 0; j < 8; ++j)
                acc[j] = fmaf(win[kx + j], w, acc[j]);
        }
    }
    float* op = f + (size_t)bc * NPIX + (oy0 + ty) * Ww + ox0 + tx * 8;
    *(float4*)(op)     = make_float4(acc[0], acc[1], acc[2], acc[3]);
    *(float4*)(op + 4) = make_float4(acc[4], acc[5], acc[6], acc[7]);
    float s = 0.f;
    #pragma unroll
    for (int j = 0; j < 8; ++j) s += acc[j];
    red[tid] = s;
    __syncthreads();
    for (int st = 128; st > 0; st >>= 1) {
        if (tid < st) red[tid] += red[tid + st];
        __syncthreads();
    }
    if (tid == 0) partial[bc * 8 + blockIdx.y * 2 + blockIdx.x] = red[0];
}

// -------------------- K2: pooled mean -> SE attention; + centers copy to out
__global__ void k_attn(const float* __restrict__ partial,
        const float* __restrict__ ca_w1, const float* __restrict__ ca_w2,
        const float* __restrict__ centers,
        float* __restrict__ attn, float* __restrict__ out) {
    __shared__ float pm[Cc];
    __shared__ float hh[CR];
    const int tid = threadIdx.x;
    const int b = blockIdx.x;
    if (b == 0) {  // centers copy (output 2)
        const size_t base = (size_t)Bc * Cc * NPIX + (size_t)Bc * NPIX;
        for (int i = tid; i < Mm * Cc; i += 128) out[base + i] = centers[i];
    }
    if (tid < Cc) {
        float s = 0.f;
        const float* p = partial + (b * Cc + tid) * 8;
        #pragma unroll
        for (int i = 0; i < 8; ++i) s += p[i];
        pm[tid] = s * (1.0f / (float)NPIX);
    }
    __syncthreads();
    if (tid < CR) {
        float s = 0.f;
        for (int c0 = 0; c0 < Cc; ++c0) s = fmaf(ca_w1[tid * Cc + c0], pm[c0], s);
        hh[tid] = fmaxf(s, 0.f);
    }
    __syncthreads();
    if (tid < Cc) {
        float s = 0.f;
        #pragma unroll
        for (int r = 0; r < CR; ++r) s = fmaf(ca_w2[tid * CR + r], hh[r], s);
        attn[b * Cc + tid] = 1.0f / (1.0f + expf(-s));
    }
}

// fast exact-enough erf (Abramowitz-Stegun 7.1.26, |err|<=1.5e-7)
__device__ __forceinline__ float fast_gelu(float v) {
    float z = fabsf(v) * 0.70710678118654752440f;
    float t = 1.0f / fmaf(0.3275911f, z, 1.0f);
    float poly = t * fmaf(t, fmaf(t, fmaf(t, fmaf(t, 1.061405429f, -1.453152027f),
                          1.421413741f), -0.284496736f), 0.254829592f);
    float e = exp2f(-1.44269504088896340736f * z * z);
    float erfz = 1.0f - poly * e;
    erfz = (v < 0.0f) ? -erfz : erfz;
    return 0.5f * v * (1.0f + erfz);
}

// -------------------- K3: attn-scale + GELU + channel-LN + offset proj
__global__ __launch_bounds__(256) void k_ln_off(const float* __restrict__ f,
        const float* __restrict__ attn, const float* __restrict__ ln_g,
        const float* __restrict__ ln_b, const float* __restrict__ off_w,
        float* __restrict__ offs) {
    __shared__ float sa[Cc], sg[Cc], sb[Cc], sw0[Cc], sw1[Cc];
    const int tid = threadIdx.x;
    const int b = blockIdx.x >> 6;
    const int pix = ((blockIdx.x & 63) << 8) + tid;
    if (tid < Cc) {
        sa[tid] = attn[b * Cc + tid];
        sg[tid] = ln_g[tid];
        sb[tid] = ln_b[tid];
        sw0[tid] = off_w[tid];
        sw1[tid] = off_w[Cc + tid];
    }
    __syncthreads();
    const float* fp = f + (size_t)b * Cc * NPIX + pix;
    float u[Cc];
    float s1 = 0.f;
    #pragma unroll
    for (int c = 0; c < Cc; ++c) {
        float g = fast_gelu(fp[(size_t)c * NPIX] * sa[c]);
        u[c] = g;
        s1 += g;
    }
    float mu = s1 * (1.0f / (float)Cc);
    float s2 = 0.f;
    #pragma unroll
    for (int c = 0; c < Cc; ++c) { float d = u[c] - mu; s2 = fmaf(d, d, s2); }
    float rs = rsqrtf(s2 * (1.0f / (float)Cc) + 1e-5f);
    float o0 = 0.f, o1 = 0.f;
    #pragma unroll
    for (int c = 0; c < Cc; ++c) {
        float v = (u[c] - mu) * rs * sg[c] + sb[c];
        o0 = fmaf(sw0[c], v, o0);
        o1 = fmaf(sw1[c], v, o1);
    }
    offs[(size_t)b * 2 * NPIX + pix] = o0;
    offs[(size_t)b * 2 * NPIX + NPIX + pix] = o1;
}

// -------------------- K4: cosine-sim cluster assignment in FP64
// per-pixel 1/||x|| is a positive scalar -> cannot change argmax -> skipped.
__global__ __launch_bounds__(256) void k_group(const float* __restrict__ x,
        const float* __restrict__ centers, int* __restrict__ gid) {
    __shared__ double scn[Mm * Cc];
    const int tid = threadIdx.x;
    for (int i = tid; i < Mm * Cc; i += 256) scn[i] = (double)centers[i];
    __syncthreads();
    if (tid < Mm) {
        double ss = 0.0;
        #pragma unroll
        for (int c = 0; c < Cc; ++c) { double v = scn[tid * Cc + c]; ss += v * v; }
        double inv = 1.0 / fmax(sqrt(ss), 1e-12);
        #pragma unroll
        for (int c = 0; c < Cc; ++c) scn[tid * Cc + c] *= inv;
    }
    __syncthreads();
    const int b = blockIdx.x >> 6;
    const int n = ((blockIdx.x & 63) << 8) + tid;
    const float* xp = x + (size_t)b * Cc * NPIX + n;
    double acc[Mm];
    #pragma unroll
    for (int m = 0; m < Mm; ++m) acc[m] = 0.0;
    for (int c = 0; c < Cc; ++c) {
        double xv = (double)xp[(size_t)c * NPIX];
        #pragma unroll
        for (int m = 0; m < Mm; ++m) acc[m] = fma(xv, scn[m * Cc + c], acc[m]);
    }
    int bi = 0;
    double bv = acc[0];
    #pragma unroll
    for (int m = 1; m < Mm; ++m) {
        if (acc[m] > bv) { bv = acc[m]; bi = m; }
    }
    gid[(size_t)b * NPIX + n] = bi;
}

// -------------------- K5: stable counting sort -> inverse perm + float perm out
__global__ __launch_bounds__(256) void k_sort(const int* __restrict__ gid,
        int* __restrict__ iperm, float* __restrict__ out) {
    __shared__ int hist[256 * Mm];
    __shared__ int tot[Mm];
    const int t = threadIdx.x;
    const int b = blockIdx.x;
    for (int i = t; i < 256 * Mm; i += 256) hist[i] = 0;
    __syncthreads();
    const int* gp = gid + (size_t)b * NPIX;
    const int base = t * 64;
    for (int i = 0; i < 64; ++i) hist[t * Mm + gp[base + i]] += 1;
    __syncthreads();
    if (t < Mm) {
        int run = 0;
        for (int r = 0; r < 256; ++r) {
            int v = hist[r * Mm + t];
            hist[r * Mm + t] = run;
            run += v;
        }
        tot[t] = run;
    }
    __syncthreads();
    if (t == 0) {
        int run = 0;
        for (int m = 0; m < Mm; ++m) { int v = tot[m]; tot[m] = run; run += v; }
    }
    __syncthreads();
    int* ip = iperm + (size_t)b * NPIX;
    float* fperm = out + (size_t)Bc * Cc * NPIX + (size_t)b * NPIX;
    for (int i = 0; i < 64; ++i) {
        int src = base + i;
        int g = gp[src];
        int pos = tot[g] + hist[t * Mm + g];
        hist[t * Mm + g] += 1;
        ip[src] = pos;            // inverse permutation (scatter destination)
        fperm[pos] = (float)src;  // output 1: perm_indices as float
    }
}

// -------------------- K6: bilinear sample of x (+R bias), scatter via iperm
// XCD-chunked swizzle: each XCD gets 128 consecutive pixel-bands (2 batches)
// so the jittered sampling windows of adjacent bands share that XCD's L2.
__global__ __launch_bounds__(256) void k_sample(const float* __restrict__ x,
        const float* __restrict__ R, const float* __restrict__ offs,
        const int* __restrict__ iperm, float* __restrict__ out) {
    const int lin = blockIdx.x;                    // 0..1023
    const int swz = (lin & 7) * 128 + (lin >> 3);  // bijective (1024 = 8*128)
    const int tid = threadIdx.x;
    const int b = swz >> 6;
    const int pix = ((swz & 63) << 8) + tid;
    const int hh = pix >> 7, wwp = pix & 127;
    float o0 = offs[(size_t)b * 2 * NPIX + pix];
    float o1 = offs[(size_t)b * 2 * NPIX + NPIX + pix];
    float gx = -1.0f + (float)wwp * (2.0f / 127.0f) + o0;
    float gy = -1.0f + (float)hh * (2.0f / 127.0f) + o1;
    float px = fminf(fmaxf((gx + 1.0f) * ((float)Ww * 0.5f) - 0.5f, 0.0f), (float)(Ww - 1));
    float py = fminf(fmaxf((gy + 1.0f) * ((float)Hh * 0.5f) - 0.5f, 0.0f), (float)(Hh - 1));
    float x0f = floorf(px), y0f = floorf(py);
    float wx = px - x0f, wy = py - y0f;
    int x0 = (int)x0f, y0 = (int)y0f;
    int x1 = min(x0 + 1, Ww - 1), y1 = min(y0 + 1, Hh - 1);
    int i00 = y0 * Ww + x0, i01 = y0 * Ww + x1;
    int i10 = y1 * Ww + x0, i11 = y1 * Ww + x1;
    float rb;
    {
        float v00 = R[i00], v01 = R[i01], v10 = R[i10], v11 = R[i11];
        float top = v00 * (1.0f - wx) + v01 * wx;
        float bot = v10 * (1.0f - wx) + v11 * wx;
        rb = top * (1.0f - wy) + bot * wy;
    }
    const int j = iperm[(size_t)b * NPIX + pix];
    const float* xp = x + (size_t)b * Cc * NPIX;
    float* op = out + (size_t)b * Cc * NPIX + j;
    for (int c = 0; c < Cc; ++c) {
        const float* xc = xp + (size_t)c * NPIX;
        float v00 = xc[i00], v01 = xc[i01], v10 = xc[i10], v11 = xc[i11];
        float top = v00 * (1.0f - wx) + v01 * wx;
        float bot = v10 * (1.0f - wx) + v11 * wx;
        op[(size_t)c * NPIX] = top * (1.0f - wy) + bot * wy + rb;
    }
}

extern "C" void kernel_launch(void* const* d_in, const int* in_sizes, int n_in,
                              void* d_out, int out_size, void* d_ws, size_t ws_size,
                              hipStream_t stream) {
    const float* x       = (const float*)d_in[0];
    const float* dw_w    = (const float*)d_in[1];
    const float* dw_b    = (const float*)d_in[2];
    const float* ca_w1   = (const float*)d_in[3];
    const float* ca_w2   = (const float*)d_in[4];
    const float* ln_g    = (const float*)d_in[5];
    const float* ln_b    = (const float*)d_in[6];
    const float* off_w   = (const float*)d_in[7];
    const float* R       = (const float*)d_in[8];
    const float* centers = (const float*)d_in[9];
    float* out = (float*)d_out;

    // workspace layout (~4.3 MB)
    float* partial = (float*)d_ws;                 // Bc*Cc*8
    float* attn    = partial + Bc * Cc * 8;        // Bc*Cc
    float* offs    = attn + Bc * Cc;               // Bc*2*NPIX
    int*   gid     = (int*)(offs + Bc * 2 * NPIX); // Bc*NPIX
    int*   iperm   = gid + Bc * NPIX;              // Bc*NPIX

    // conv output f lives in d_out's map region; dead after k_ln_off, then
    // safely overwritten by k_sample's permuted scatter writes.
    float* f = out;

    hipLaunchKernelGGL(k_conv, dim3(Ww / CTW, Hh / CTH, Bc * Cc), dim3(256), 0,
                       stream, x, dw_w, dw_b, f, partial);
    hipLaunchKernelGGL(k_attn, dim3(Bc), dim3(128), 0, stream,
                       partial, ca_w1, ca_w2, centers, attn, out);
    hipLaunchKernelGGL(k_ln_off, dim3(1024), dim3(256), 0, stream,
                       f, attn, ln_g, ln_b, off_w, offs);
    hipLaunchKernelGGL(k_group, dim3(1024), dim3(256), 0, stream, x, centers, gid);
    hipLaunchKernelGGL(k_sort, dim3(Bc), dim3(256), 0, stream, gid, iperm, out);
    hipLaunchKernelGGL(k_sample, dim3(1024), dim3(256), 0, stream,
                       x, R, offs, iperm, out);
}

// Round 5
// 354.049 us; speedup vs baseline: 1.9351x; 1.0591x over previous
//
#include <hip/hip_runtime.h>
#include <math.h>

#define Bc 16
#define Cc 96
#define Hh 128
#define Ww 128
#define NPIX 16384
#define Mm 12
#define CR 6
#define PAD 3

// conv tile geometry: 32 rows x 64 cols of output per 256-thread block,
// each thread produces 8 horizontal outputs via in-register sliding window.
#define CTH 32
#define CTW 64
#define TROWS 38          // CTH + 6
#define TCOLS 70          // CTW + 6
#define TSTRIDE 76        // padded: bank-group (3*ty+2*tx)%8 uniform -> conflict-free

// k_sample channel split: 6 groups x 16 channels
#define CGROUPS 6
#define CPG 16

// -------------------- K1: depthwise 7x7 conv + bias, per-block pool partials
__global__ __launch_bounds__(256) void k_conv(const float* __restrict__ x,
        const float* __restrict__ dw_w, const float* __restrict__ dw_b,
        float* __restrict__ f, float* __restrict__ partial) {
    const int bc = blockIdx.z;             // b*Cc + c
    const int c = bc % Cc;
    __shared__ float tile[TROWS * TSTRIDE];
    __shared__ float wts[49];
    __shared__ float red[256];
    const int tid = threadIdx.x;
    if (tid < 49) wts[tid] = dw_w[c * 49 + tid];
    const int ox0 = blockIdx.x * CTW, oy0 = blockIdx.y * CTH;
    const float* xp = x + (size_t)bc * NPIX;
    for (int i = tid; i < TROWS * TCOLS; i += 256) {
        int r = i / TCOLS, cc2 = i % TCOLS;
        int gy = oy0 + r - PAD, gx = ox0 + cc2 - PAD;
        float v = 0.f;
        if (gy >= 0 && gy < Hh && gx >= 0 && gx < Ww) v = xp[gy * Ww + gx];
        tile[r * TSTRIDE + cc2] = v;
    }
    __syncthreads();
    const int tx = tid & 7;    // col-group: outputs ox0 + tx*8 + 0..7
    const int ty = tid >> 3;   // output row 0..31
    const float bias = dw_b[c];
    float acc[8];
    #pragma unroll
    for (int j = 0; j < 8; ++j) acc[j] = bias;
    #pragma unroll
    for (int ky = 0; ky < 7; ++ky) {
        const float* rowp = &tile[(ty + ky) * TSTRIDE + tx * 8];
        float4 a = *(const float4*)(rowp);
        float4 b4 = *(const float4*)(rowp + 4);
        float4 c4 = *(const float4*)(rowp + 8);
        float4 d4 = *(const float4*)(rowp + 12);
        float win[16] = {a.x, a.y, a.z, a.w, b4.x, b4.y, b4.z, b4.w,
                         c4.x, c4.y, c4.z, c4.w, d4.x, d4.y, d4.z, d4.w};
        #pragma unroll
        for (int kx = 0; kx < 7; ++kx) {
            float w = wts[ky * 7 + kx];
            #pragma unroll
            for (int j = 0; j < 8; ++j)
                acc[j] = fmaf(win[kx + j], w, acc[j]);
        }
    }
    float* op = f + (size_t)bc * NPIX + (oy0 + ty) * Ww + ox0 + tx * 8;
    *(float4*)(op)     = make_float4(acc[0], acc[1], acc[2], acc[3]);
    *(float4*)(op + 4) = make_float4(acc[4], acc[5], acc[6], acc[7]);
    float s = 0.f;
    #pragma unroll
    for (int j = 0; j < 8; ++j) s += acc[j];
    red[tid] = s;
    __syncthreads();
    for (int st = 128; st > 0; st >>= 1) {
        if (tid < st) red[tid] += red[tid + st];
        __syncthreads();
    }
    if (tid == 0) partial[bc * 8 + blockIdx.y * 2 + blockIdx.x] = red[0];
}

// -------------------- K2: pooled mean -> SE attention; + centers copy to out
__global__ void k_attn(const float* __restrict__ partial,
        const float* __restrict__ ca_w1, const float* __restrict__ ca_w2,
        const float* __restrict__ centers,
        float* __restrict__ attn, float* __restrict__ out) {
    __shared__ float pm[Cc];
    __shared__ float hh[CR];
    const int tid = threadIdx.x;
    const int b = blockIdx.x;
    if (b == 0) {  // centers copy (output 2)
        const size_t base = (size_t)Bc * Cc * NPIX + (size_t)Bc * NPIX;
        for (int i = tid; i < Mm * Cc; i += 128) out[base + i] = centers[i];
    }
    if (tid < Cc) {
        float s = 0.f;
        const float* p = partial + (b * Cc + tid) * 8;
        #pragma unroll
        for (int i = 0; i < 8; ++i) s += p[i];
        pm[tid] = s * (1.0f / (float)NPIX);
    }
    __syncthreads();
    if (tid < CR) {
        float s = 0.f;
        for (int c0 = 0; c0 < Cc; ++c0) s = fmaf(ca_w1[tid * Cc + c0], pm[c0], s);
        hh[tid] = fmaxf(s, 0.f);
    }
    __syncthreads();
    if (tid < Cc) {
        float s = 0.f;
        #pragma unroll
        for (int r = 0; r < CR; ++r) s = fmaf(ca_w2[tid * CR + r], hh[r], s);
        attn[b * Cc + tid] = 1.0f / (1.0f + expf(-s));
    }
}

// fast exact-enough erf (Abramowitz-Stegun 7.1.26, |err|<=1.5e-7)
__device__ __forceinline__ float fast_gelu(float v) {
    float z = fabsf(v) * 0.70710678118654752440f;
    float t = 1.0f / fmaf(0.3275911f, z, 1.0f);
    float poly = t * fmaf(t, fmaf(t, fmaf(t, fmaf(t, 1.061405429f, -1.453152027f),
                          1.421413741f), -0.284496736f), 0.254829592f);
    float e = exp2f(-1.44269504088896340736f * z * z);
    float erfz = 1.0f - poly * e;
    erfz = (v < 0.0f) ? -erfz : erfz;
    return 0.5f * v * (1.0f + erfz);
}

// -------------------- K3: attn-scale + GELU + channel-LN + offset proj
__global__ __launch_bounds__(256) void k_ln_off(const float* __restrict__ f,
        const float* __restrict__ attn, const float* __restrict__ ln_g,
        const float* __restrict__ ln_b, const float* __restrict__ off_w,
        float* __restrict__ offs) {
    __shared__ float sa[Cc], sg[Cc], sb[Cc], sw0[Cc], sw1[Cc];
    const int tid = threadIdx.x;
    const int b = blockIdx.x >> 6;
    const int pix = ((blockIdx.x & 63) << 8) + tid;
    if (tid < Cc) {
        sa[tid] = attn[b * Cc + tid];
        sg[tid] = ln_g[tid];
        sb[tid] = ln_b[tid];
        sw0[tid] = off_w[tid];
        sw1[tid] = off_w[Cc + tid];
    }
    __syncthreads();
    const float* fp = f + (size_t)b * Cc * NPIX + pix;
    float u[Cc];
    float s1 = 0.f;
    #pragma unroll
    for (int c = 0; c < Cc; ++c) {
        float g = fast_gelu(fp[(size_t)c * NPIX] * sa[c]);
        u[c] = g;
        s1 += g;
    }
    float mu = s1 * (1.0f / (float)Cc);
    float s2 = 0.f;
    #pragma unroll
    for (int c = 0; c < Cc; ++c) { float d = u[c] - mu; s2 = fmaf(d, d, s2); }
    float rs = rsqrtf(s2 * (1.0f / (float)Cc) + 1e-5f);
    float o0 = 0.f, o1 = 0.f;
    #pragma unroll
    for (int c = 0; c < Cc; ++c) {
        float v = (u[c] - mu) * rs * sg[c] + sb[c];
        o0 = fmaf(sw0[c], v, o0);
        o1 = fmaf(sw1[c], v, o1);
    }
    offs[(size_t)b * 2 * NPIX + pix] = o0;
    offs[(size_t)b * 2 * NPIX + NPIX + pix] = o1;
}

// -------------------- K4: cosine-sim cluster assignment in FP64
// per-pixel 1/||x|| is a positive scalar -> cannot change argmax -> skipped.
__global__ __launch_bounds__(256) void k_group(const float* __restrict__ x,
        const float* __restrict__ centers, int* __restrict__ gid) {
    __shared__ double scn[Mm * Cc];
    const int tid = threadIdx.x;
    for (int i = tid; i < Mm * Cc; i += 256) scn[i] = (double)centers[i];
    __syncthreads();
    if (tid < Mm) {
        double ss = 0.0;
        #pragma unroll
        for (int c = 0; c < Cc; ++c) { double v = scn[tid * Cc + c]; ss += v * v; }
        double inv = 1.0 / fmax(sqrt(ss), 1e-12);
        #pragma unroll
        for (int c = 0; c < Cc; ++c) scn[tid * Cc + c] *= inv;
    }
    __syncthreads();
    const int b = blockIdx.x >> 6;
    const int n = ((blockIdx.x & 63) << 8) + tid;
    const float* xp = x + (size_t)b * Cc * NPIX + n;
    double acc[Mm];
    #pragma unroll
    for (int m = 0; m < Mm; ++m) acc[m] = 0.0;
    for (int c = 0; c < Cc; ++c) {
        double xv = (double)xp[(size_t)c * NPIX];
        #pragma unroll
        for (int m = 0; m < Mm; ++m) acc[m] = fma(xv, scn[m * Cc + c], acc[m]);
    }
    int bi = 0;
    double bv = acc[0];
    #pragma unroll
    for (int m = 1; m < Mm; ++m) {
        if (acc[m] > bv) { bv = acc[m]; bi = m; }
    }
    gid[(size_t)b * NPIX + n] = bi;
}

// -------------------- K5: stable counting sort -> inverse perm + float perm out
__global__ __launch_bounds__(256) void k_sort(const int* __restrict__ gid,
        int* __restrict__ iperm, float* __restrict__ out) {
    __shared__ int hist[256 * Mm];
    __shared__ int tot[Mm];
    const int t = threadIdx.x;
    const int b = blockIdx.x;
    for (int i = t; i < 256 * Mm; i += 256) hist[i] = 0;
    __syncthreads();
    const int* gp = gid + (size_t)b * NPIX;
    const int base = t * 64;
    for (int i = 0; i < 64; ++i) hist[t * Mm + gp[base + i]] += 1;
    __syncthreads();
    if (t < Mm) {
        int run = 0;
        for (int r = 0; r < 256; ++r) {
            int v = hist[r * Mm + t];
            hist[r * Mm + t] = run;
            run += v;
        }
        tot[t] = run;
    }
    __syncthreads();
    if (t == 0) {
        int run = 0;
        for (int m = 0; m < Mm; ++m) { int v = tot[m]; tot[m] = run; run += v; }
    }
    __syncthreads();
    int* ip = iperm + (size_t)b * NPIX;
    float* fperm = out + (size_t)Bc * Cc * NPIX + (size_t)b * NPIX;
    for (int i = 0; i < 64; ++i) {
        int src = base + i;
        int g = gp[src];
        int pos = tot[g] + hist[t * Mm + g];
        hist[t * Mm + g] += 1;
        ip[src] = pos;            // inverse permutation (scatter destination)
        fperm[pos] = (float)src;  // output 1: perm_indices as float
    }
}

// -------------------- K6: bilinear sample of x (+R bias), scatter via iperm
// grid = (1024 bands, CGROUPS channel groups). XCD-chunked swizzle on bands;
// each channel group redoes the cheap coord math, reads its 16 planes.
__global__ __launch_bounds__(256) void k_sample(const float* __restrict__ x,
        const float* __restrict__ R, const float* __restrict__ offs,
        const int* __restrict__ iperm, float* __restrict__ out) {
    const int lin = blockIdx.x;                    // 0..1023
    const int swz = (lin & 7) * 128 + (lin >> 3);  // bijective (1024 = 8*128)
    const int tid = threadIdx.x;
    const int b = swz >> 6;
    const int pix = ((swz & 63) << 8) + tid;
    const int hh = pix >> 7, wwp = pix & 127;
    float o0 = offs[(size_t)b * 2 * NPIX + pix];
    float o1 = offs[(size_t)b * 2 * NPIX + NPIX + pix];
    float gx = -1.0f + (float)wwp * (2.0f / 127.0f) + o0;
    float gy = -1.0f + (float)hh * (2.0f / 127.0f) + o1;
    float px = fminf(fmaxf((gx + 1.0f) * ((float)Ww * 0.5f) - 0.5f, 0.0f), (float)(Ww - 1));
    float py = fminf(fmaxf((gy + 1.0f) * ((float)Hh * 0.5f) - 0.5f, 0.0f), (float)(Hh - 1));
    float x0f = floorf(px), y0f = floorf(py);
    float wx = px - x0f, wy = py - y0f;
    int x0 = (int)x0f, y0 = (int)y0f;
    int x1 = min(x0 + 1, Ww - 1), y1 = min(y0 + 1, Hh - 1);
    int i00 = y0 * Ww + x0, i01 = y0 * Ww + x1;
    int i10 = y1 * Ww + x0, i11 = y1 * Ww + x1;
    const int c0 = blockIdx.y * CPG;
    float rb = 0.f;
    if (blockIdx.y == 0) {  // R bias folded into channel-group 0's writes? NO:
        // rb must be added to EVERY channel. Compute it in all groups (cheap).
    }
    {
        float v00 = R[i00], v01 = R[i01], v10 = R[i10], v11 = R[i11];
        float top = v00 * (1.0f - wx) + v01 * wx;
        float bot = v10 * (1.0f - wx) + v11 * wx;
        rb = top * (1.0f - wy) + bot * wy;
    }
    const int j = iperm[(size_t)b * NPIX + pix];
    const float* xp = x + (size_t)b * Cc * NPIX + (size_t)c0 * NPIX;
    float* op = out + (size_t)b * Cc * NPIX + (size_t)c0 * NPIX + j;
    #pragma unroll
    for (int c = 0; c < CPG; ++c) {
        const float* xc = xp + (size_t)c * NPIX;
        float v00 = xc[i00], v01 = xc[i01], v10 = xc[i10], v11 = xc[i11];
        float top = v00 * (1.0f - wx) + v01 * wx;
        float bot = v10 * (1.0f - wx) + v11 * wx;
        op[(size_t)c * NPIX] = top * (1.0f - wy) + bot * wy + rb;
    }
}

extern "C" void kernel_launch(void* const* d_in, const int* in_sizes, int n_in,
                              void* d_out, int out_size, void* d_ws, size_t ws_size,
                              hipStream_t stream) {
    const float* x       = (const float*)d_in[0];
    const float* dw_w    = (const float*)d_in[1];
    const float* dw_b    = (const float*)d_in[2];
    const float* ca_w1   = (const float*)d_in[3];
    const float* ca_w2   = (const float*)d_in[4];
    const float* ln_g    = (const float*)d_in[5];
    const float* ln_b    = (const float*)d_in[6];
    const float* off_w   = (const float*)d_in[7];
    const float* R       = (const float*)d_in[8];
    const float* centers = (const float*)d_in[9];
    float* out = (float*)d_out;

    // workspace layout (~4.3 MB)
    float* partial = (float*)d_ws;                 // Bc*Cc*8
    float* attn    = partial + Bc * Cc * 8;        // Bc*Cc
    float* offs    = attn + Bc * Cc;               // Bc*2*NPIX
    int*   gid     = (int*)(offs + Bc * 2 * NPIX); // Bc*NPIX
    int*   iperm   = gid + Bc * NPIX;              // Bc*NPIX

    // conv output f lives in d_out's map region; dead after k_ln_off, then
    // safely overwritten by k_sample's permuted scatter writes.
    float* f = out;

    hipLaunchKernelGGL(k_conv, dim3(Ww / CTW, Hh / CTH, Bc * Cc), dim3(256), 0,
                       stream, x, dw_w, dw_b, f, partial);
    hipLaunchKernelGGL(k_attn, dim3(Bc), dim3(128), 0, stream,
                       partial, ca_w1, ca_w2, centers, attn, out);
    hipLaunchKernelGGL(k_ln_off, dim3(1024), dim3(256), 0, stream,
                       f, attn, ln_g, ln_b, off_w, offs);
    hipLaunchKernelGGL(k_group, dim3(1024), dim3(256), 0, stream, x, centers, gid);
    hipLaunchKernelGGL(k_sort, dim3(Bc), dim3(256), 0, stream, gid, iperm, out);
    hipLaunchKernelGGL(k_sample, dim3(1024, CGROUPS), dim3(256), 0, stream,
                       x, R, offs, iperm, out);
}

// Round 6
// 332.530 us; speedup vs baseline: 2.0603x; 1.0647x over previous
//
#include <hip/hip_runtime.h>
#include <math.h>

#define Bc 16
#define Cc 96
#define Hh 128
#define Ww 128
#define NPIX 16384
#define Mm 12
#define CR 6
#define PAD 3

// conv tile geometry: 32 rows x 64 cols of output per 256-thread block,
// each thread produces 8 horizontal outputs via in-register sliding window.
#define CTH 32
#define CTW 64
#define TROWS 38          // CTH + 6
#define TCOLS 70          // CTW + 6
#define TSTRIDE 76        // padded: bank-group (3*ty+2*tx)%8 uniform -> conflict-free

// k_sample channel split: 6 groups x 16 channels
#define CGROUPS 6
#define CPG 16

// 8B vector load with honest 4B alignment (gfx950 unaligned global access
// emits global_load_dwordx2; fallback is 2x dword = no worse than before).
typedef float f2 __attribute__((ext_vector_type(2), aligned(4)));

// -------------------- K1: depthwise 7x7 conv + bias, per-block pool partials
__global__ __launch_bounds__(256) void k_conv(const float* __restrict__ x,
        const float* __restrict__ dw_w, const float* __restrict__ dw_b,
        float* __restrict__ f, float* __restrict__ partial) {
    const int bc = blockIdx.z;             // b*Cc + c
    const int c = bc % Cc;
    __shared__ float tile[TROWS * TSTRIDE];
    __shared__ float wts[49];
    __shared__ float red[256];
    const int tid = threadIdx.x;
    if (tid < 49) wts[tid] = dw_w[c * 49 + tid];
    const int ox0 = blockIdx.x * CTW, oy0 = blockIdx.y * CTH;
    const float* xp = x + (size_t)bc * NPIX;
    for (int i = tid; i < TROWS * TCOLS; i += 256) {
        int r = i / TCOLS, cc2 = i % TCOLS;
        int gy = oy0 + r - PAD, gx = ox0 + cc2 - PAD;
        float v = 0.f;
        if (gy >= 0 && gy < Hh && gx >= 0 && gx < Ww) v = xp[gy * Ww + gx];
        tile[r * TSTRIDE + cc2] = v;
    }
    __syncthreads();
    const int tx = tid & 7;    // col-group: outputs ox0 + tx*8 + 0..7
    const int ty = tid >> 3;   // output row 0..31
    const float bias = dw_b[c];
    float acc[8];
    #pragma unroll
    for (int j = 0; j < 8; ++j) acc[j] = bias;
    #pragma unroll
    for (int ky = 0; ky < 7; ++ky) {
        const float* rowp = &tile[(ty + ky) * TSTRIDE + tx * 8];
        float4 a = *(const float4*)(rowp);
        float4 b4 = *(const float4*)(rowp + 4);
        float4 c4 = *(const float4*)(rowp + 8);
        float4 d4 = *(const float4*)(rowp + 12);
        float win[16] = {a.x, a.y, a.z, a.w, b4.x, b4.y, b4.z, b4.w,
                         c4.x, c4.y, c4.z, c4.w, d4.x, d4.y, d4.z, d4.w};
        #pragma unroll
        for (int kx = 0; kx < 7; ++kx) {
            float w = wts[ky * 7 + kx];
            #pragma unroll
            for (int j = 0; j < 8; ++j)
                acc[j] = fmaf(win[kx + j], w, acc[j]);
        }
    }
    float* op = f + (size_t)bc * NPIX + (oy0 + ty) * Ww + ox0 + tx * 8;
    *(float4*)(op)     = make_float4(acc[0], acc[1], acc[2], acc[3]);
    *(float4*)(op + 4) = make_float4(acc[4], acc[5], acc[6], acc[7]);
    float s = 0.f;
    #pragma unroll
    for (int j = 0; j < 8; ++j) s += acc[j];
    red[tid] = s;
    __syncthreads();
    for (int st = 128; st > 0; st >>= 1) {
        if (tid < st) red[tid] += red[tid + st];
        __syncthreads();
    }
    if (tid == 0) partial[bc * 8 + blockIdx.y * 2 + blockIdx.x] = red[0];
}

// -------------------- K2: pooled mean -> SE attention; + centers copy to out
__global__ void k_attn(const float* __restrict__ partial,
        const float* __restrict__ ca_w1, const float* __restrict__ ca_w2,
        const float* __restrict__ centers,
        float* __restrict__ attn, float* __restrict__ out) {
    __shared__ float pm[Cc];
    __shared__ float hh[CR];
    const int tid = threadIdx.x;
    const int b = blockIdx.x;
    if (b == 0) {  // centers copy (output 2)
        const size_t base = (size_t)Bc * Cc * NPIX + (size_t)Bc * NPIX;
        for (int i = tid; i < Mm * Cc; i += 128) out[base + i] = centers[i];
    }
    if (tid < Cc) {
        float s = 0.f;
        const float* p = partial + (b * Cc + tid) * 8;
        #pragma unroll
        for (int i = 0; i < 8; ++i) s += p[i];
        pm[tid] = s * (1.0f / (float)NPIX);
    }
    __syncthreads();
    if (tid < CR) {
        float s = 0.f;
        for (int c0 = 0; c0 < Cc; ++c0) s = fmaf(ca_w1[tid * Cc + c0], pm[c0], s);
        hh[tid] = fmaxf(s, 0.f);
    }
    __syncthreads();
    if (tid < Cc) {
        float s = 0.f;
        #pragma unroll
        for (int r = 0; r < CR; ++r) s = fmaf(ca_w2[tid * CR + r], hh[r], s);
        attn[b * Cc + tid] = 1.0f / (1.0f + expf(-s));
    }
}

// fast exact-enough erf (Abramowitz-Stegun 7.1.26, |err|<=1.5e-7)
__device__ __forceinline__ float fast_gelu(float v) {
    float z = fabsf(v) * 0.70710678118654752440f;
    float t = 1.0f / fmaf(0.3275911f, z, 1.0f);
    float poly = t * fmaf(t, fmaf(t, fmaf(t, fmaf(t, 1.061405429f, -1.453152027f),
                          1.421413741f), -0.284496736f), 0.254829592f);
    float e = exp2f(-1.44269504088896340736f * z * z);
    float erfz = 1.0f - poly * e;
    erfz = (v < 0.0f) ? -erfz : erfz;
    return 0.5f * v * (1.0f + erfz);
}

// -------------------- K3: attn-scale + GELU + channel-LN + offset proj
__global__ __launch_bounds__(256) void k_ln_off(const float* __restrict__ f,
        const float* __restrict__ attn, const float* __restrict__ ln_g,
        const float* __restrict__ ln_b, const float* __restrict__ off_w,
        float* __restrict__ offs) {
    __shared__ float sa[Cc], sg[Cc], sb[Cc], sw0[Cc], sw1[Cc];
    const int tid = threadIdx.x;
    const int b = blockIdx.x >> 6;
    const int pix = ((blockIdx.x & 63) << 8) + tid;
    if (tid < Cc) {
        sa[tid] = attn[b * Cc + tid];
        sg[tid] = ln_g[tid];
        sb[tid] = ln_b[tid];
        sw0[tid] = off_w[tid];
        sw1[tid] = off_w[Cc + tid];
    }
    __syncthreads();
    const float* fp = f + (size_t)b * Cc * NPIX + pix;
    float u[Cc];
    float s1 = 0.f;
    #pragma unroll
    for (int c = 0; c < Cc; ++c) {
        float g = fast_gelu(fp[(size_t)c * NPIX] * sa[c]);
        u[c] = g;
        s1 += g;
    }
    float mu = s1 * (1.0f / (float)Cc);
    float s2 = 0.f;
    #pragma unroll
    for (int c = 0; c < Cc; ++c) { float d = u[c] - mu; s2 = fmaf(d, d, s2); }
    float rs = rsqrtf(s2 * (1.0f / (float)Cc) + 1e-5f);
    float o0 = 0.f, o1 = 0.f;
    #pragma unroll
    for (int c = 0; c < Cc; ++c) {
        float v = (u[c] - mu) * rs * sg[c] + sb[c];
        o0 = fmaf(sw0[c], v, o0);
        o1 = fmaf(sw1[c], v, o1);
    }
    offs[(size_t)b * 2 * NPIX + pix] = o0;
    offs[(size_t)b * 2 * NPIX + NPIX + pix] = o1;
}

// -------------------- K4: cosine-sim cluster assignment in FP64
// per-pixel 1/||x|| is a positive scalar -> cannot change argmax -> skipped.
__global__ __launch_bounds__(256) void k_group(const float* __restrict__ x,
        const float* __restrict__ centers, int* __restrict__ gid) {
    __shared__ double scn[Mm * Cc];
    const int tid = threadIdx.x;
    for (int i = tid; i < Mm * Cc; i += 256) scn[i] = (double)centers[i];
    __syncthreads();
    if (tid < Mm) {
        double ss = 0.0;
        #pragma unroll
        for (int c = 0; c < Cc; ++c) { double v = scn[tid * Cc + c]; ss += v * v; }
        double inv = 1.0 / fmax(sqrt(ss), 1e-12);
        #pragma unroll
        for (int c = 0; c < Cc; ++c) scn[tid * Cc + c] *= inv;
    }
    __syncthreads();
    const int b = blockIdx.x >> 6;
    const int n = ((blockIdx.x & 63) << 8) + tid;
    const float* xp = x + (size_t)b * Cc * NPIX + n;
    double acc[Mm];
    #pragma unroll
    for (int m = 0; m < Mm; ++m) acc[m] = 0.0;
    for (int c = 0; c < Cc; ++c) {
        double xv = (double)xp[(size_t)c * NPIX];
        #pragma unroll
        for (int m = 0; m < Mm; ++m) acc[m] = fma(xv, scn[m * Cc + c], acc[m]);
    }
    int bi = 0;
    double bv = acc[0];
    #pragma unroll
    for (int m = 1; m < Mm; ++m) {
        if (acc[m] > bv) { bv = acc[m]; bi = m; }
    }
    gid[(size_t)b * NPIX + n] = bi;
}

// -------------------- K5: stable counting sort -> inverse perm + float perm out
__global__ __launch_bounds__(256) void k_sort(const int* __restrict__ gid,
        int* __restrict__ iperm, float* __restrict__ out) {
    __shared__ int hist[256 * Mm];
    __shared__ int tot[Mm];
    const int t = threadIdx.x;
    const int b = blockIdx.x;
    for (int i = t; i < 256 * Mm; i += 256) hist[i] = 0;
    __syncthreads();
    const int* gp = gid + (size_t)b * NPIX;
    const int base = t * 64;
    for (int i = 0; i < 64; ++i) hist[t * Mm + gp[base + i]] += 1;
    __syncthreads();
    if (t < Mm) {
        int run = 0;
        for (int r = 0; r < 256; ++r) {
            int v = hist[r * Mm + t];
            hist[r * Mm + t] = run;
            run += v;
        }
        tot[t] = run;
    }
    __syncthreads();
    if (t == 0) {
        int run = 0;
        for (int m = 0; m < Mm; ++m) { int v = tot[m]; tot[m] = run; run += v; }
    }
    __syncthreads();
    int* ip = iperm + (size_t)b * NPIX;
    float* fperm = out + (size_t)Bc * Cc * NPIX + (size_t)b * NPIX;
    for (int i = 0; i < 64; ++i) {
        int src = base + i;
        int g = gp[src];
        int pos = tot[g] + hist[t * Mm + g];
        hist[t * Mm + g] += 1;
        ip[src] = pos;            // inverse permutation (scatter destination)
        fperm[pos] = (float)src;  // output 1: perm_indices as float
    }
}

// -------------------- K6: bilinear sample of x (+R bias), scatter via iperm
// Row-pair taps (x0,x0+1) fetched as ONE 8B load -> one L2 sector per row
// instead of two independent dword gathers (L1 thrashes at 22 waves/CU).
// Clamp case x0==127: base=min(x0,126), wx==0 exactly, select covers v00.
__global__ __launch_bounds__(256) void k_sample(const float* __restrict__ x,
        const float* __restrict__ R, const float* __restrict__ offs,
        const int* __restrict__ iperm, float* __restrict__ out) {
    const int lin = blockIdx.x;                    // 0..1023
    const int swz = (lin & 7) * 128 + (lin >> 3);  // bijective (1024 = 8*128)
    const int tid = threadIdx.x;
    const int b = swz >> 6;
    const int pix = ((swz & 63) << 8) + tid;
    const int hh = pix >> 7, wwp = pix & 127;
    float o0 = offs[(size_t)b * 2 * NPIX + pix];
    float o1 = offs[(size_t)b * 2 * NPIX + NPIX + pix];
    float gx = -1.0f + (float)wwp * (2.0f / 127.0f) + o0;
    float gy = -1.0f + (float)hh * (2.0f / 127.0f) + o1;
    float px = fminf(fmaxf((gx + 1.0f) * ((float)Ww * 0.5f) - 0.5f, 0.0f), (float)(Ww - 1));
    float py = fminf(fmaxf((gy + 1.0f) * ((float)Hh * 0.5f) - 0.5f, 0.0f), (float)(Hh - 1));
    float x0f = floorf(px), y0f = floorf(py);
    float wx = px - x0f, wy = py - y0f;
    int x0 = (int)x0f, y0 = (int)y0f;
    int y1 = min(y0 + 1, Hh - 1);
    const bool hi = (x0 == Ww - 1);        // then wx == 0 exactly
    const int xb = hi ? (Ww - 2) : x0;     // 8B window [xb, xb+1]
    const int r0 = y0 * Ww + xb, r1 = y1 * Ww + xb;
    float rb;
    {
        f2 t0 = *(const f2*)(R + r0);
        f2 t1 = *(const f2*)(R + r1);
        float v00 = hi ? t0.y : t0.x, v01 = t0.y;
        float v10 = hi ? t1.y : t1.x, v11 = t1.y;
        float top = v00 * (1.0f - wx) + v01 * wx;
        float bot = v10 * (1.0f - wx) + v11 * wx;
        rb = top * (1.0f - wy) + bot * wy;
    }
    const int c0 = blockIdx.y * CPG;
    const int j = iperm[(size_t)b * NPIX + pix];
    const float* xp = x + (size_t)b * Cc * NPIX + (size_t)c0 * NPIX;
    float* op = out + (size_t)b * Cc * NPIX + (size_t)c0 * NPIX + j;
    f2 t0[CPG], t1[CPG];
    #pragma unroll
    for (int c = 0; c < CPG; ++c) {        // batch all loads: deep MLP
        const float* xc = xp + (size_t)c * NPIX;
        t0[c] = *(const f2*)(xc + r0);
        t1[c] = *(const f2*)(xc + r1);
    }
    #pragma unroll
    for (int c = 0; c < CPG; ++c) {
        float v00 = hi ? t0[c].y : t0[c].x, v01 = t0[c].y;
        float v10 = hi ? t1[c].y : t1[c].x, v11 = t1[c].y;
        float top = v00 * (1.0f - wx) + v01 * wx;
        float bot = v10 * (1.0f - wx) + v11 * wx;
        op[(size_t)c * NPIX] = top * (1.0f - wy) + bot * wy + rb;
    }
}

extern "C" void kernel_launch(void* const* d_in, const int* in_sizes, int n_in,
                              void* d_out, int out_size, void* d_ws, size_t ws_size,
                              hipStream_t stream) {
    const float* x       = (const float*)d_in[0];
    const float* dw_w    = (const float*)d_in[1];
    const float* dw_b    = (const float*)d_in[2];
    const float* ca_w1   = (const float*)d_in[3];
    const float* ca_w2   = (const float*)d_in[4];
    const float* ln_g    = (const float*)d_in[5];
    const float* ln_b    = (const float*)d_in[6];
    const float* off_w   = (const float*)d_in[7];
    const float* R       = (const float*)d_in[8];
    const float* centers = (const float*)d_in[9];
    float* out = (float*)d_out;

    // workspace layout (~4.3 MB)
    float* partial = (float*)d_ws;                 // Bc*Cc*8
    float* attn    = partial + Bc * Cc * 8;        // Bc*Cc
    float* offs    = attn + Bc * Cc;               // Bc*2*NPIX
    int*   gid     = (int*)(offs + Bc * 2 * NPIX); // Bc*NPIX
    int*   iperm   = gid + Bc * NPIX;              // Bc*NPIX

    // conv output f lives in d_out's map region; dead after k_ln_off, then
    // safely overwritten by k_sample's permuted scatter writes.
    float* f = out;

    hipLaunchKernelGGL(k_conv, dim3(Ww / CTW, Hh / CTH, Bc * Cc), dim3(256), 0,
                       stream, x, dw_w, dw_b, f, partial);
    hipLaunchKernelGGL(k_attn, dim3(Bc), dim3(128), 0, stream,
                       partial, ca_w1, ca_w2, centers, attn, out);
    hipLaunchKernelGGL(k_ln_off, dim3(1024), dim3(256), 0, stream,
                       f, attn, ln_g, ln_b, off_w, offs);
    hipLaunchKernelGGL(k_group, dim3(1024), dim3(256), 0, stream, x, centers, gid);
    hipLaunchKernelGGL(k_sort, dim3(Bc), dim3(256), 0, stream, gid, iperm, out);
    hipLaunchKernelGGL(k_sample, dim3(1024, CGROUPS), dim3(256), 0, stream,
                       x, R, offs, iperm, out);
}

// Round 7
// 332.219 us; speedup vs baseline: 2.0623x; 1.0009x over previous
//
#include <hip/hip_runtime.h>
#include <math.h>

#define Bc 16
#define Cc 96
#define Hh 128
#define Ww 128
#define NPIX 16384
#define Mm 12
#define CR 6
#define PAD 3

// conv tile geometry: 32 rows x 64 cols of output per 256-thread block,
// each thread produces 8 horizontal outputs via in-register sliding window.
#define CTH 32
#define CTW 64
#define TROWS 38          // CTH + 6
#define TCOLS 70          // CTW + 6
#define TSTRIDE 76        // padded: bank-group (3*ty+2*tx)%8 uniform -> conflict-free

// k_sample channel split: 6 groups x 16 channels
#define CGROUPS 6
#define CPG 16

// 8B vector load with honest 4B alignment (gfx950 unaligned global access
// emits global_load_dwordx2; fallback is 2x dword = no worse than before).
typedef float f2 __attribute__((ext_vector_type(2), aligned(4)));

// -------------------- K1: depthwise 7x7 conv + bias, per-block pool partials
__global__ __launch_bounds__(256) void k_conv(const float* __restrict__ x,
        const float* __restrict__ dw_w, const float* __restrict__ dw_b,
        float* __restrict__ f, float* __restrict__ partial) {
    const int bc = blockIdx.z;             // b*Cc + c
    const int c = bc % Cc;
    __shared__ float tile[TROWS * TSTRIDE];
    __shared__ float wts[49];
    __shared__ float red[256];
    const int tid = threadIdx.x;
    if (tid < 49) wts[tid] = dw_w[c * 49 + tid];
    const int ox0 = blockIdx.x * CTW, oy0 = blockIdx.y * CTH;
    const float* xp = x + (size_t)bc * NPIX;
    for (int i = tid; i < TROWS * TCOLS; i += 256) {
        int r = i / TCOLS, cc2 = i % TCOLS;
        int gy = oy0 + r - PAD, gx = ox0 + cc2 - PAD;
        float v = 0.f;
        if (gy >= 0 && gy < Hh && gx >= 0 && gx < Ww) v = xp[gy * Ww + gx];
        tile[r * TSTRIDE + cc2] = v;
    }
    __syncthreads();
    const int tx = tid & 7;    // col-group: outputs ox0 + tx*8 + 0..7
    const int ty = tid >> 3;   // output row 0..31
    const float bias = dw_b[c];
    float acc[8];
    #pragma unroll
    for (int j = 0; j < 8; ++j) acc[j] = bias;
    #pragma unroll
    for (int ky = 0; ky < 7; ++ky) {
        const float* rowp = &tile[(ty + ky) * TSTRIDE + tx * 8];
        float4 a = *(const float4*)(rowp);
        float4 b4 = *(const float4*)(rowp + 4);
        float4 c4 = *(const float4*)(rowp + 8);
        float4 d4 = *(const float4*)(rowp + 12);
        float win[16] = {a.x, a.y, a.z, a.w, b4.x, b4.y, b4.z, b4.w,
                         c4.x, c4.y, c4.z, c4.w, d4.x, d4.y, d4.z, d4.w};
        #pragma unroll
        for (int kx = 0; kx < 7; ++kx) {
            float w = wts[ky * 7 + kx];
            #pragma unroll
            for (int j = 0; j < 8; ++j)
                acc[j] = fmaf(win[kx + j], w, acc[j]);
        }
    }
    float* op = f + (size_t)bc * NPIX + (oy0 + ty) * Ww + ox0 + tx * 8;
    *(float4*)(op)     = make_float4(acc[0], acc[1], acc[2], acc[3]);
    *(float4*)(op + 4) = make_float4(acc[4], acc[5], acc[6], acc[7]);
    float s = 0.f;
    #pragma unroll
    for (int j = 0; j < 8; ++j) s += acc[j];
    red[tid] = s;
    __syncthreads();
    for (int st = 128; st > 0; st >>= 1) {
        if (tid < st) red[tid] += red[tid + st];
        __syncthreads();
    }
    if (tid == 0) partial[bc * 8 + blockIdx.y * 2 + blockIdx.x] = red[0];
}

// -------------------- K2: pooled mean -> SE attention; + centers copy to out
__global__ void k_attn(const float* __restrict__ partial,
        const float* __restrict__ ca_w1, const float* __restrict__ ca_w2,
        const float* __restrict__ centers,
        float* __restrict__ attn, float* __restrict__ out) {
    __shared__ float pm[Cc];
    __shared__ float hh[CR];
    const int tid = threadIdx.x;
    const int b = blockIdx.x;
    if (b == 0) {  // centers copy (output 2)
        const size_t base = (size_t)Bc * Cc * NPIX + (size_t)Bc * NPIX;
        for (int i = tid; i < Mm * Cc; i += 128) out[base + i] = centers[i];
    }
    if (tid < Cc) {
        float s = 0.f;
        const float* p = partial + (b * Cc + tid) * 8;
        #pragma unroll
        for (int i = 0; i < 8; ++i) s += p[i];
        pm[tid] = s * (1.0f / (float)NPIX);
    }
    __syncthreads();
    if (tid < CR) {
        float s = 0.f;
        for (int c0 = 0; c0 < Cc; ++c0) s = fmaf(ca_w1[tid * Cc + c0], pm[c0], s);
        hh[tid] = fmaxf(s, 0.f);
    }
    __syncthreads();
    if (tid < Cc) {
        float s = 0.f;
        #pragma unroll
        for (int r = 0; r < CR; ++r) s = fmaf(ca_w2[tid * CR + r], hh[r], s);
        attn[b * Cc + tid] = 1.0f / (1.0f + expf(-s));
    }
}

// fast exact-enough erf (Abramowitz-Stegun 7.1.26, |err|<=1.5e-7)
__device__ __forceinline__ float fast_gelu(float v) {
    float z = fabsf(v) * 0.70710678118654752440f;
    float t = 1.0f / fmaf(0.3275911f, z, 1.0f);
    float poly = t * fmaf(t, fmaf(t, fmaf(t, fmaf(t, 1.061405429f, -1.453152027f),
                          1.421413741f), -0.284496736f), 0.254829592f);
    float e = exp2f(-1.44269504088896340736f * z * z);
    float erfz = 1.0f - poly * e;
    erfz = (v < 0.0f) ? -erfz : erfz;
    return 0.5f * v * (1.0f + erfz);
}

// -------------------- K3: attn-scale + GELU + channel-LN + offset proj
__global__ __launch_bounds__(256) void k_ln_off(const float* __restrict__ f,
        const float* __restrict__ attn, const float* __restrict__ ln_g,
        const float* __restrict__ ln_b, const float* __restrict__ off_w,
        float* __restrict__ offs) {
    __shared__ float sa[Cc], sg[Cc], sb[Cc], sw0[Cc], sw1[Cc];
    const int tid = threadIdx.x;
    const int b = blockIdx.x >> 6;
    const int pix = ((blockIdx.x & 63) << 8) + tid;
    if (tid < Cc) {
        sa[tid] = attn[b * Cc + tid];
        sg[tid] = ln_g[tid];
        sb[tid] = ln_b[tid];
        sw0[tid] = off_w[tid];
        sw1[tid] = off_w[Cc + tid];
    }
    __syncthreads();
    const float* fp = f + (size_t)b * Cc * NPIX + pix;
    float u[Cc];
    float s1 = 0.f;
    #pragma unroll
    for (int c = 0; c < Cc; ++c) {
        float g = fast_gelu(fp[(size_t)c * NPIX] * sa[c]);
        u[c] = g;
        s1 += g;
    }
    float mu = s1 * (1.0f / (float)Cc);
    float s2 = 0.f;
    #pragma unroll
    for (int c = 0; c < Cc; ++c) { float d = u[c] - mu; s2 = fmaf(d, d, s2); }
    float rs = rsqrtf(s2 * (1.0f / (float)Cc) + 1e-5f);
    float o0 = 0.f, o1 = 0.f;
    #pragma unroll
    for (int c = 0; c < Cc; ++c) {
        float v = (u[c] - mu) * rs * sg[c] + sb[c];
        o0 = fmaf(sw0[c], v, o0);
        o1 = fmaf(sw1[c], v, o1);
    }
    offs[(size_t)b * 2 * NPIX + pix] = o0;
    offs[(size_t)b * 2 * NPIX + NPIX + pix] = o1;
}

// -------------------- K4: cosine-sim cluster assignment in FP64
// per-pixel 1/||x|| is a positive scalar -> cannot change argmax -> skipped.
__global__ __launch_bounds__(256) void k_group(const float* __restrict__ x,
        const float* __restrict__ centers, int* __restrict__ gid) {
    __shared__ double scn[Mm * Cc];
    const int tid = threadIdx.x;
    for (int i = tid; i < Mm * Cc; i += 256) scn[i] = (double)centers[i];
    __syncthreads();
    if (tid < Mm) {
        double ss = 0.0;
        #pragma unroll
        for (int c = 0; c < Cc; ++c) { double v = scn[tid * Cc + c]; ss += v * v; }
        double inv = 1.0 / fmax(sqrt(ss), 1e-12);
        #pragma unroll
        for (int c = 0; c < Cc; ++c) scn[tid * Cc + c] *= inv;
    }
    __syncthreads();
    const int b = blockIdx.x >> 6;
    const int n = ((blockIdx.x & 63) << 8) + tid;
    const float* xp = x + (size_t)b * Cc * NPIX + n;
    double acc[Mm];
    #pragma unroll
    for (int m = 0; m < Mm; ++m) acc[m] = 0.0;
    for (int c = 0; c < Cc; ++c) {
        double xv = (double)xp[(size_t)c * NPIX];
        #pragma unroll
        for (int m = 0; m < Mm; ++m) acc[m] = fma(xv, scn[m * Cc + c], acc[m]);
    }
    int bi = 0;
    double bv = acc[0];
    #pragma unroll
    for (int m = 1; m < Mm; ++m) {
        if (acc[m] > bv) { bv = acc[m]; bi = m; }
    }
    gid[(size_t)b * NPIX + n] = bi;
}

// -------------------- K5: stable counting sort -> inverse perm + float perm out
__global__ __launch_bounds__(256) void k_sort(const int* __restrict__ gid,
        int* __restrict__ iperm, float* __restrict__ out) {
    __shared__ int hist[256 * Mm];
    __shared__ int tot[Mm];
    const int t = threadIdx.x;
    const int b = blockIdx.x;
    for (int i = t; i < 256 * Mm; i += 256) hist[i] = 0;
    __syncthreads();
    const int* gp = gid + (size_t)b * NPIX;
    const int base = t * 64;
    for (int i = 0; i < 64; ++i) hist[t * Mm + gp[base + i]] += 1;
    __syncthreads();
    if (t < Mm) {
        int run = 0;
        for (int r = 0; r < 256; ++r) {
            int v = hist[r * Mm + t];
            hist[r * Mm + t] = run;
            run += v;
        }
        tot[t] = run;
    }
    __syncthreads();
    if (t == 0) {
        int run = 0;
        for (int m = 0; m < Mm; ++m) { int v = tot[m]; tot[m] = run; run += v; }
    }
    __syncthreads();
    int* ip = iperm + (size_t)b * NPIX;
    float* fperm = out + (size_t)Bc * Cc * NPIX + (size_t)b * NPIX;
    for (int i = 0; i < 64; ++i) {
        int src = base + i;
        int g = gp[src];
        int pos = tot[g] + hist[t * Mm + g];
        hist[t * Mm + g] += 1;
        ip[src] = pos;            // inverse permutation (scatter destination)
        fperm[pos] = (float)src;  // output 1: perm_indices as float
    }
}

// -------------------- K6: bilinear sample of x (+R bias), scatter via iperm
// __launch_bounds__(256,4): VGPR cap 128 so the compiler can keep all 32 f2
// gather results in flight (round-6 build chose 44 VGPRs -> ~5-deep MLP ->
// latency-bound at 145us with every pipe idle).
__global__ __launch_bounds__(256, 4) void k_sample(const float* __restrict__ x,
        const float* __restrict__ R, const float* __restrict__ offs,
        const int* __restrict__ iperm, float* __restrict__ out) {
    const int lin = blockIdx.x;                    // 0..1023
    const int swz = (lin & 7) * 128 + (lin >> 3);  // bijective (1024 = 8*128)
    const int tid = threadIdx.x;
    const int b = swz >> 6;
    const int pix = ((swz & 63) << 8) + tid;
    const int hh = pix >> 7, wwp = pix & 127;
    float o0 = offs[(size_t)b * 2 * NPIX + pix];
    float o1 = offs[(size_t)b * 2 * NPIX + NPIX + pix];
    float gx = -1.0f + (float)wwp * (2.0f / 127.0f) + o0;
    float gy = -1.0f + (float)hh * (2.0f / 127.0f) + o1;
    float px = fminf(fmaxf((gx + 1.0f) * ((float)Ww * 0.5f) - 0.5f, 0.0f), (float)(Ww - 1));
    float py = fminf(fmaxf((gy + 1.0f) * ((float)Hh * 0.5f) - 0.5f, 0.0f), (float)(Hh - 1));
    float x0f = floorf(px), y0f = floorf(py);
    float wx = px - x0f, wy = py - y0f;
    int x0 = (int)x0f, y0 = (int)y0f;
    int y1 = min(y0 + 1, Hh - 1);
    const bool hi = (x0 == Ww - 1);        // then wx == 0 exactly
    const int xb = hi ? (Ww - 2) : x0;     // 8B window [xb, xb+1]
    const int r0 = y0 * Ww + xb, r1 = y1 * Ww + xb;
    float rb;
    {
        f2 t0 = *(const f2*)(R + r0);
        f2 t1 = *(const f2*)(R + r1);
        float v00 = hi ? t0.y : t0.x, v01 = t0.y;
        float v10 = hi ? t1.y : t1.x, v11 = t1.y;
        float top = v00 * (1.0f - wx) + v01 * wx;
        float bot = v10 * (1.0f - wx) + v11 * wx;
        rb = top * (1.0f - wy) + bot * wy;
    }
    const int c0 = blockIdx.y * CPG;
    const int j = iperm[(size_t)b * NPIX + pix];
    const float* xp = x + (size_t)b * Cc * NPIX + (size_t)c0 * NPIX;
    float* op = out + (size_t)b * Cc * NPIX + (size_t)c0 * NPIX + j;
    f2 t0[CPG], t1[CPG];
    #pragma unroll
    for (int c = 0; c < CPG; ++c) {        // batch all loads: deep MLP
        const float* xc = xp + (size_t)c * NPIX;
        t0[c] = *(const f2*)(xc + r0);
        t1[c] = *(const f2*)(xc + r1);
    }
    #pragma unroll
    for (int c = 0; c < CPG; ++c) {
        float v00 = hi ? t0[c].y : t0[c].x, v01 = t0[c].y;
        float v10 = hi ? t1[c].y : t1[c].x, v11 = t1[c].y;
        float top = v00 * (1.0f - wx) + v01 * wx;
        float bot = v10 * (1.0f - wx) + v11 * wx;
        op[(size_t)c * NPIX] = top * (1.0f - wy) + bot * wy + rb;
    }
}

extern "C" void kernel_launch(void* const* d_in, const int* in_sizes, int n_in,
                              void* d_out, int out_size, void* d_ws, size_t ws_size,
                              hipStream_t stream) {
    const float* x       = (const float*)d_in[0];
    const float* dw_w    = (const float*)d_in[1];
    const float* dw_b    = (const float*)d_in[2];
    const float* ca_w1   = (const float*)d_in[3];
    const float* ca_w2   = (const float*)d_in[4];
    const float* ln_g    = (const float*)d_in[5];
    const float* ln_b    = (const float*)d_in[6];
    const float* off_w   = (const float*)d_in[7];
    const float* R       = (const float*)d_in[8];
    const float* centers = (const float*)d_in[9];
    float* out = (float*)d_out;

    // workspace layout (~4.3 MB)
    float* partial = (float*)d_ws;                 // Bc*Cc*8
    float* attn    = partial + Bc * Cc * 8;        // Bc*Cc
    float* offs    = attn + Bc * Cc;               // Bc*2*NPIX
    int*   gid     = (int*)(offs + Bc * 2 * NPIX); // Bc*NPIX
    int*   iperm   = gid + Bc * NPIX;              // Bc*NPIX

    // conv output f lives in d_out's map region; dead after k_ln_off, then
    // safely overwritten by k_sample's permuted scatter writes.
    float* f = out;

    hipLaunchKernelGGL(k_conv, dim3(Ww / CTW, Hh / CTH, Bc * Cc), dim3(256), 0,
                       stream, x, dw_w, dw_b, f, partial);
    hipLaunchKernelGGL(k_attn, dim3(Bc), dim3(128), 0, stream,
                       partial, ca_w1, ca_w2, centers, attn, out);
    hipLaunchKernelGGL(k_ln_off, dim3(1024), dim3(256), 0, stream,
                       f, attn, ln_g, ln_b, off_w, offs);
    hipLaunchKernelGGL(k_group, dim3(1024), dim3(256), 0, stream, x, centers, gid);
    hipLaunchKernelGGL(k_sort, dim3(Bc), dim3(256), 0, stream, gid, iperm, out);
    hipLaunchKernelGGL(k_sample, dim3(1024, CGROUPS), dim3(256), 0, stream,
                       x, R, offs, iperm, out);
}